// Round 14
// baseline (254.555 us; speedup 1.0000x reference)
//
#include <hip/hip_runtime.h>

#define D 128
#define BN_EPS 1e-5f
#define NBUCK 512     // coarse buckets, dst>>8 (391 used at N=100K), 256 nodes/bucket
#define BSHIFT 8
#define BNODES 256    // nodes per bucket
#define CAP 4608      // padded slots/bucket; mean fill 4096 (+8 sigma)
#define PBCHUNK 6272  // LDS-staged edges per pB block

using short8 = __attribute__((ext_vector_type(8))) short;
using floatx4 = __attribute__((ext_vector_type(4))) float;

__device__ inline unsigned short f2bf(float f) {
    unsigned u = __float_as_uint(f);
    u += 0x7fff + ((u >> 16) & 1);  // RNE
    return (unsigned short)(u >> 16);
}
__device__ inline float bf2f(unsigned short s) {
    return __uint_as_float(((unsigned)s) << 16);
}

// ---------- init: zero resCnt + Wt transpose + BN affine (tiny, 1 node) ----
__global__ __launch_bounds__(256) void init_kernel(
    const float* __restrict__ W, const float* __restrict__ b,
    const float* __restrict__ gamma, const float* __restrict__ beta,
    const float* __restrict__ mean, const float* __restrict__ var,
    unsigned short* __restrict__ Wt, float* __restrict__ scv,
    float* __restrict__ pov, int* __restrict__ resCnt) {
    int t = blockIdx.x * 256 + threadIdx.x;  // 0..16383 == D*D
    Wt[(size_t)(t & 127) * D + (t >> 7)] = f2bf(W[t]);
    if (t < NBUCK) resCnt[t] = 0;
    if (t < D) {
        float sc = gamma[t] * rsqrtf(var[t] + BN_EPS);
        scv[t] = sc;
        pov[t] = (b[t] - mean[t]) * sc + beta[t];
    }
}

// ---------- pB: partition into CAPACITY-PADDED buckets, LDS-staged ----------
// (R13-proven.) Two-pass within the block: scatter the chunk into LDS
// bucket-ordered (ord+bkt, ~43KB), then a LINEAR out-copy -> every pairs
// line is written in one temporal burst (no ~25x L2 line-RMW thrash).
// pairs entry = (dst&255)<<24 | src (valid: N < 2^24). Run base =
// bucket*CAP + atomicAdd(resCnt). Overflow drops here, recovered later.
__global__ __launch_bounds__(512) void pB_kernel(const int* __restrict__ src,
                                                 const int* __restrict__ dst,
                                                 int* __restrict__ resCnt,
                                                 unsigned int* __restrict__ pairs,
                                                 int E) {
    __shared__ int lh[NBUCK];        // hist, then lcur
    __shared__ int excl[NBUCK];      // scan scratch, then exclusive offsets
    __shared__ int resBase[NBUCK];   // global run base per bucket
    __shared__ unsigned int ord[PBCHUNK];
    __shared__ unsigned short bkt[PBCHUNK];
    int tid = threadIdx.x;
    lh[tid] = 0;
    __syncthreads();
    int chunk = (E + gridDim.x - 1) / gridDim.x;  // <= PBCHUNK by grid choice
    int base = blockIdx.x * chunk;
    int lim = min(chunk, E - base);
    if (lim <= 0) return;
    for (int i = tid; i < lim; i += 512) atomicAdd(&lh[dst[base + i] >> BSHIFT], 1);
    __syncthreads();
    int c = lh[tid];
    excl[tid] = c;
    __syncthreads();
    for (int d = 1; d < NBUCK; d <<= 1) {
        int v = (tid >= d) ? excl[tid - d] : 0;
        __syncthreads();
        excl[tid] += v;
        __syncthreads();
    }
    int myExcl = excl[tid] - c;  // exclusive local offset for bucket tid
    resBase[tid] = tid * CAP + (c ? atomicAdd(&resCnt[tid], c) : 0);
    __syncthreads();
    excl[tid] = myExcl;
    lh[tid] = myExcl;  // lcur
    __syncthreads();
    // pass 2: scatter chunk into LDS, bucket-ordered
    for (int i = tid; i < lim; i += 512) {
        int s = src[base + i], d2 = dst[base + i];
        int b2 = d2 >> BSHIFT;
        int pos = atomicAdd(&lh[b2], 1);
        ord[pos] = (((unsigned)d2 & 255u) << 24) | (unsigned)s;
        bkt[pos] = (unsigned short)b2;
    }
    __syncthreads();
    // out-copy: linear; consecutive i in a bucket -> consecutive global dest
    for (int i = tid; i < lim; i += 512) {
        int b2 = bkt[i];
        int dest = resBase[b2] + (i - excl[b2]);
        if (dest < (b2 + 1) * CAP) pairs[dest] = ord[i];
    }
}

// ---------- bscan: global exclusive scan of resCnt -> cbase (ONE block) ----
// Replaces every sortxs block's redundant 512-wide 18-barrier scan.
__global__ __launch_bounds__(512) void bscan_kernel(const int* __restrict__ resCnt,
                                                    int* __restrict__ cbase) {
    __shared__ int a[NBUCK];
    int t = threadIdx.x;
    int orig = resCnt[t];
    a[t] = orig;
    __syncthreads();
    for (int d = 1; d < NBUCK; d <<= 1) {
        int v = (t >= d) ? a[t - d] : 0;
        __syncthreads();
        a[t] += v;
        __syncthreads();
    }
    cbase[t] = a[t] - orig;
}

// ---------- sortxs: per-bucket counting sort + premult xs build ----------
// R14 slimming: (a) cbase comes from bscan (no per-block NBUCK scan);
// (b) the bucket's pairs (<=18.4KB) are staged in LDS once -- hist and
// scatter both read LDS, halving pairs traffic and the dependent-load chain.
// Overflow bucket (cnt>CAP): offs=-1 marker, deg/dinv from full edge scan.
__global__ __launch_bounds__(512) void sortxs_kernel(
    const unsigned int* __restrict__ pairs, const int* __restrict__ resCnt,
    const int* __restrict__ cbasev, const int* __restrict__ src,
    const int* __restrict__ dst, const float* __restrict__ x,
    int* __restrict__ deg, int* __restrict__ offs, int* __restrict__ colidx,
    float* __restrict__ dinv, unsigned short* __restrict__ xs, int N, int E) {
    __shared__ unsigned int sp[CAP];  // 18.4KB staged pairs
    __shared__ int lh[BNODES];
    __shared__ int lcur[BNODES];
    __shared__ float sdv[BNODES];
    int tid = threadIdx.x;
    int b = blockIdx.x;
    int cnt = resCnt[b];
    int cbase = cbasev[b];        // compact colidx base (from bscan)
    int pbase = b * CAP;          // padded pairs base
    if (tid < BNODES) lh[tid] = 0;

    if (cnt <= CAP) {
        // ---- normal path: stage pairs in LDS ----
        for (int i = tid; i < cnt; i += 512) sp[i] = pairs[pbase + i];
        __syncthreads();  // covers lh zero + sp stage
        for (int i = tid; i < cnt; i += 512) atomicAdd(&lh[sp[i] >> 24], 1);
        __syncthreads();
        int orig = (tid < BNODES) ? lh[tid] : 0;
        for (int d = 1; d < BNODES; d <<= 1) {
            int v = (tid < BNODES && tid >= d) ? lh[tid - d] : 0;
            __syncthreads();
            if (tid < BNODES) lh[tid] += v;
            __syncthreads();
        }
        if (tid < BNODES) {
            int exc = lh[tid] - orig;
            int node = b * BNODES + tid;
            float dvv = rsqrtf((float)(orig + 1));
            sdv[tid] = dvv;
            if (node < N) {
                deg[node] = orig;
                offs[node] = cbase + exc;
                dinv[node] = dvv;
            }
            lcur[tid] = exc;
        }
        if (b == 0 && tid == 0) offs[N] = E;
        __syncthreads();
        for (int i = tid; i < cnt; i += 512) {
            unsigned int p = sp[i];
            int pos = atomicAdd(&lcur[p >> 24], 1);
            colidx[cbase + pos] = (int)(p & 0x00FFFFFFu);
        }
    } else {
        // ---- overflow recovery: exact deg from full edge scan; no colidx ----
        __syncthreads();  // lh zero visible
        for (int i = tid; i < E; i += 512) {
            int d2 = dst[i];
            if ((d2 >> BSHIFT) == b) atomicAdd(&lh[d2 & 255], 1);
        }
        __syncthreads();
        if (tid < BNODES) {
            int orig = lh[tid];
            int node = b * BNODES + tid;
            float dvv = rsqrtf((float)(orig + 1));
            sdv[tid] = dvv;
            if (node < N) {
                deg[node] = orig;
                offs[node] = -1;  // agg falls back to full scan for this node
                dinv[node] = dvv;
            }
        }
        if (b == 0 && tid == 0) offs[N] = E;
        __syncthreads();
    }

    // ---- xs build for this bucket's nodes: xs = bf16(dinv[n] * x[n]) ----
    int nb = min(BNODES, N - b * BNODES);
    if (nb > 0) {
        const float4* x4 = (const float4*)x;
        ushort4* xs4 = (ushort4*)xs;
        int tot = nb * 32;  // 32 float4 chunks per node
        for (int c2 = tid; c2 < tot; c2 += 512) {
            int nl = c2 >> 5, q = c2 & 31;
            int node = b * BNODES + nl;
            float dvv = sdv[nl];
            float4 f = x4[(size_t)node * 32 + q];
            ushort4 o;
            o.x = f2bf(dvv * f.x); o.y = f2bf(dvv * f.y);
            o.z = f2bf(dvv * f.z); o.w = f2bf(dvv * f.w);
            xs4[(size_t)node * 32 + q] = o;
        }
    }
}

// ---------- fallback kernels (small-ws path) ----------
__global__ void wt_kernel(const float* __restrict__ W, const float* __restrict__ b,
                          const float* __restrict__ gamma, const float* __restrict__ beta,
                          const float* __restrict__ mean, const float* __restrict__ var,
                          unsigned short* __restrict__ Wt, float* __restrict__ scv,
                          float* __restrict__ pov) {
    int t = blockIdx.x * blockDim.x + threadIdx.x;
    int k = t >> 7, n = t & 127;
    Wt[(size_t)n * D + k] = f2bf(W[t]);
    if (t < D) {
        float sc = gamma[t] * rsqrtf(var[t] + BN_EPS);
        scv[t] = sc;
        pov[t] = (b[t] - mean[t]) * sc + beta[t];
    }
}

__global__ void deg_kernel(const int* __restrict__ dst, int* __restrict__ deg, int E) {
    int e = blockIdx.x * blockDim.x + threadIdx.x;
    if (e < E) atomicAdd(&deg[dst[e]], 1);
}

__global__ void dinv_kernel(const int* __restrict__ deg, float* __restrict__ dinv, int N) {
    int v = blockIdx.x * blockDim.x + threadIdx.x;
    if (v < N) dinv[v] = rsqrtf((float)(deg[v] + 1));
}

__global__ __launch_bounds__(256) void scan1_kernel(const int* __restrict__ deg,
                                                    int* __restrict__ bsum, int N) {
    __shared__ int s[256];
    int t = threadIdx.x;
    int v = blockIdx.x * 256 + t;
    s[t] = (v < N) ? deg[v] : 0;
    for (int st = 128; st > 0; st >>= 1) {
        __syncthreads();
        if (t < st) s[t] += s[t + st];
    }
    if (t == 0) bsum[blockIdx.x] = s[0];
}

__global__ __launch_bounds__(512) void scan2_kernel(int* __restrict__ bsum,
                                                    int* __restrict__ offs, int P, int N) {
    __shared__ int a[512];
    int t = threadIdx.x;
    int orig = (t < P) ? bsum[t] : 0;
    a[t] = orig;
    __syncthreads();
    for (int d = 1; d < 512; d <<= 1) {
        int tv = (t >= d) ? a[t - d] : 0;
        __syncthreads();
        a[t] += tv;
        __syncthreads();
    }
    if (t < P) bsum[t] = a[t] - orig;
    if (t == 0) offs[N] = a[511];
}

__global__ __launch_bounds__(256) void scan3_kernel(const int* __restrict__ deg,
                                                    const int* __restrict__ bsum,
                                                    int* __restrict__ offs,
                                                    int* __restrict__ cursor, int N) {
    __shared__ int a[256];
    int t = threadIdx.x;
    int v = blockIdx.x * 256 + t;
    int d = (v < N) ? deg[v] : 0;
    a[t] = d;
    __syncthreads();
    for (int st = 1; st < 256; st <<= 1) {
        int tv = (t >= st) ? a[t - st] : 0;
        __syncthreads();
        a[t] += tv;
        __syncthreads();
    }
    if (v < N) {
        int off = bsum[blockIdx.x] + a[t] - d;
        offs[v] = off;
        cursor[v] = off;
    }
}

__global__ void fill_kernel(const int* __restrict__ src, const int* __restrict__ dst,
                            int* __restrict__ cursor, int* __restrict__ colidx, int E) {
    int e = blockIdx.x * blockDim.x + threadIdx.x;
    if (e < E) {
        int d = dst[e];
        int pos = atomicAdd(&cursor[d], 1);
        colidx[pos] = src[e];
    }
}

// ---------- gather-aggregate: one wave/node, lane = 2 packed cols ----------
// R4/R9-proven body; pe = offs + deg (supports overflow marker offs<0).
__global__ __launch_bounds__(256) void agg_kernel(
    const float* __restrict__ x, const unsigned short* __restrict__ xs,
    const float* __restrict__ dinv, const int* __restrict__ offs,
    const int* __restrict__ deg, const int* __restrict__ colidx,
    const int* __restrict__ src, const int* __restrict__ dst,
    float* __restrict__ outp, unsigned int* __restrict__ aggb, int N, int E) {
    int wid = (blockIdx.x * blockDim.x + threadIdx.x) >> 6;
    if (wid >= N) return;
    int lane = threadIdx.x & 63;
    float dv = dinv[wid];
    float a0, a1;
    int p = offs[wid];
    if (xs) {
        const unsigned int* xs32 = (const unsigned int*)xs;
        unsigned int sv = xs32[(size_t)wid * 64 + lane];
        a0 = bf2f((unsigned short)sv);
        a1 = bf2f((unsigned short)(sv >> 16));
        if (p >= 0) {
            int pe = p + deg[wid];
            for (; p + 16 <= pe; p += 16) {
                int u[16];
                unsigned int v[16];
#pragma unroll
                for (int j = 0; j < 16; ++j) u[j] = colidx[p + j];
#pragma unroll
                for (int j = 0; j < 16; ++j) v[j] = xs32[(size_t)u[j] * 64 + lane];
#pragma unroll
                for (int j = 0; j < 16; ++j) {
                    a0 += bf2f((unsigned short)v[j]);
                    a1 += bf2f((unsigned short)(v[j] >> 16));
                }
            }
            for (; p + 4 <= pe; p += 4) {
                int u[4];
                unsigned int v[4];
#pragma unroll
                for (int j = 0; j < 4; ++j) u[j] = colidx[p + j];
#pragma unroll
                for (int j = 0; j < 4; ++j) v[j] = xs32[(size_t)u[j] * 64 + lane];
#pragma unroll
                for (int j = 0; j < 4; ++j) {
                    a0 += bf2f((unsigned short)v[j]);
                    a1 += bf2f((unsigned short)(v[j] >> 16));
                }
            }
            for (; p < pe; ++p) {
                unsigned int v = xs32[(size_t)colidx[p] * 64 + lane];
                a0 += bf2f((unsigned short)v);
                a1 += bf2f((unsigned short)(v >> 16));
            }
        } else {
            // overflow-bucket node: gather via full edge scan (never on bench)
            for (int e = 0; e < E; ++e) {
                if (dst[e] == wid) {
                    unsigned int v = xs32[(size_t)src[e] * 64 + lane];
                    a0 += bf2f((unsigned short)v);
                    a1 += bf2f((unsigned short)(v >> 16));
                }
            }
        }
        aggb[(size_t)wid * 64 + lane] =
            (unsigned int)f2bf(dv * a0) | ((unsigned int)f2bf(dv * a1) << 16);
    } else {
        const float2* x2 = (const float2*)x;
        float2 s = x2[(size_t)wid * 64 + lane];
        a0 = dv * s.x;
        a1 = dv * s.y;
        int pe = p + deg[wid];
        for (; p < pe; ++p) {
            int u = colidx[p];
            float du = dinv[u];
            float2 vv = x2[(size_t)u * 64 + lane];
            a0 += du * vv.x;
            a1 += du * vv.y;
        }
        float2 r;
        r.x = dv * a0;
        r.y = dv * a1;
        ((float2*)outp)[(size_t)wid * 64 + lane] = r;
    }
}

// ---------- MFMA GEMM: out = relu(BN(agg @ W + b)) + x (R4 body, no nt) ----
__global__ __launch_bounds__(256) void gemm_kernel(
    float* __restrict__ outp, const float* __restrict__ xg,
    const unsigned short* __restrict__ Wt, const unsigned short* __restrict__ aggb,
    const float* __restrict__ scv, const float* __restrict__ pov, int nTiles) {
    __shared__ uint4 sW4[2048];  // 32KB: [row 0..127][c4 0..15] swizzled c4^=(row&7)
    int tid = threadIdx.x;
    const uint4* W4 = (const uint4*)Wt;
#pragma unroll
    for (int i = 0; i < 8; ++i) {
        int q = tid + i * 256;  // uint4 index 0..2047
        int row = q >> 4, c4 = q & 15;
        sW4[row * 16 + (c4 ^ (row & 7))] = W4[q];
    }
    __syncthreads();

    int wid = (blockIdx.x * blockDim.x + tid) >> 6;
    if (wid >= nTiles) return;
    int lane = tid & 63;
    int m = lane & 15, quad = lane >> 4;
    int row0 = wid * 16;

    short8 A[4];
    if (aggb) {
        const unsigned short* arow = aggb + (size_t)(row0 + m) * D;
#pragma unroll
        for (int ks = 0; ks < 4; ++ks)
            A[ks] = *(const short8*)&arow[ks * 32 + quad * 8];
    } else {
        const float* arow = outp + (size_t)(row0 + m) * D;
#pragma unroll
        for (int ks = 0; ks < 4; ++ks) {
            float4 f0 = *(const float4*)(arow + ks * 32 + quad * 8);
            float4 f1 = *(const float4*)(arow + ks * 32 + quad * 8 + 4);
            short8 af;
            af[0] = (short)f2bf(f0.x); af[1] = (short)f2bf(f0.y);
            af[2] = (short)f2bf(f0.z); af[3] = (short)f2bf(f0.w);
            af[4] = (short)f2bf(f1.x); af[5] = (short)f2bf(f1.y);
            af[6] = (short)f2bf(f1.z); af[7] = (short)f2bf(f1.w);
            A[ks] = af;
        }
    }

#pragma unroll
    for (int cg2 = 0; cg2 < 8; ++cg2) {
        int brow = cg2 * 16 + m;
        floatx4 acc = {0.f, 0.f, 0.f, 0.f};
#pragma unroll
        for (int ks = 0; ks < 4; ++ks) {
            short8 Bf = *(const short8*)&sW4[brow * 16 + ((ks * 4 + quad) ^ (m & 7))];
            acc = __builtin_amdgcn_mfma_f32_16x16x32_bf16(A[ks], Bf, acc, 0, 0, 0);
        }
        int col = cg2 * 16 + m;
        float sc = scv[col], po = pov[col];
#pragma unroll
        for (int i = 0; i < 4; ++i) {
            int row = row0 + quad * 4 + i;
            float bn = acc[i] * sc + po;
            size_t idx = (size_t)row * D + col;
            outp[idx] = fmaxf(bn, 0.f) + xg[idx];
        }
    }
}

extern "C" void kernel_launch(void* const* d_in, const int* in_sizes, int n_in,
                              void* d_out, int out_size, void* d_ws, size_t ws_size,
                              hipStream_t stream) {
    const float* x = (const float*)d_in[0];
    const int* edge = (const int*)d_in[1];
    const float* Wm = (const float*)d_in[2];
    const float* b = (const float*)d_in[3];
    const float* gamma = (const float*)d_in[4];
    const float* beta = (const float*)d_in[5];
    const float* mean = (const float*)d_in[6];
    const float* var = (const float*)d_in[7];
    float* out = (float*)d_out;

    int N = in_sizes[0] / D;
    int E = in_sizes[1] / 2;
    const int* src = edge;
    const int* dst = edge + E;
    int P = (N + 255) / 256;

    // ---- workspace layout (fixed area identical to proven R4 footprint) ----
    char* w = (char*)d_ws;
    size_t cur = 0;
    auto take = [&](size_t bytes) -> void* {
        cur = (cur + 15) & ~(size_t)15;
        void* p = w + cur;
        cur += bytes;
        return p;
    };
    int* deg = (int*)take((size_t)N * 4);
    int* resCnt = (int*)take(NBUCK * 4);
    float* dinv = (float*)take((size_t)N * 4);
    int* offs = (int*)take((size_t)(N + 1) * 4);
    int* cursor = (int*)take((size_t)N * 4);  // fast path: cbase[0..NBUCK)
    int* bsum = (int*)take((size_t)(P + 1) * 4);
    unsigned short* Wt = (unsigned short*)take((size_t)D * D * 2);
    float* scv = (float*)take(D * 4);
    float* pov = (float*)take(D * 4);
    int* colidx = (int*)take((size_t)E * 4);
    cur = (cur + 15) & ~(size_t)15;
    size_t fixedEnd = cur;

    size_t xsBytes = (size_t)N * D * 2;
    size_t pairsBytes = (size_t)NBUCK * CAP * 4;  // padded packed-u32 pairs
    size_t zoneBytes = (xsBytes > pairsBytes) ? xsBytes : pairsBytes;
    bool fast = (fixedEnd + xsBytes + zoneBytes <= ws_size) && (N < (1 << 24)) &&
                (N >= NBUCK);

    unsigned short* xs = nullptr;
    unsigned int* pairs = nullptr;
    unsigned int* aggb = nullptr;
    if (fast) {
        xs = (unsigned short*)(w + fixedEnd);
        pairs = (unsigned int*)(w + fixedEnd + xsBytes);  // dead after sortxs
        aggb = (unsigned int*)(w + fixedEnd + xsBytes);   // aliases pairs
    }

    if (fast) {
        int pgrid = (E + PBCHUNK - 1) / PBCHUNK;  // chunk <= PBCHUNK by construction
        int* cbase = cursor;  // fast path reuse (cursor is fallback-only)
        init_kernel<<<(D * D) / 256, 256, 0, stream>>>(Wm, b, gamma, beta, mean, var,
                                                       Wt, scv, pov, resCnt);
        pB_kernel<<<pgrid, 512, 0, stream>>>(src, dst, resCnt, pairs, E);
        bscan_kernel<<<1, 512, 0, stream>>>(resCnt, cbase);
        sortxs_kernel<<<NBUCK, 512, 0, stream>>>(pairs, resCnt, cbase, src, dst, x, deg,
                                                 offs, colidx, dinv, xs, N, E);
        agg_kernel<<<(N * 64 + 255) / 256, 256, 0, stream>>>(
            x, xs, dinv, offs, deg, colidx, src, dst, out, aggb, N, E);
        int nTiles = (N + 15) / 16;
        gemm_kernel<<<(nTiles * 64 + 255) / 256, 256, 0, stream>>>(
            out, x, Wt, (const unsigned short*)aggb, scv, pov, nTiles);
    } else {
        wt_kernel<<<(D * D) / 256, 256, 0, stream>>>(Wm, b, gamma, beta, mean, var, Wt,
                                                     scv, pov);
        hipMemsetAsync(deg, 0, sizeof(int) * N, stream);
        deg_kernel<<<(E + 255) / 256, 256, 0, stream>>>(dst, deg, E);
        dinv_kernel<<<(N + 255) / 256, 256, 0, stream>>>(deg, dinv, N);
        scan1_kernel<<<P, 256, 0, stream>>>(deg, bsum, N);
        scan2_kernel<<<1, 512, 0, stream>>>(bsum, offs, P, N);
        scan3_kernel<<<P, 256, 0, stream>>>(deg, bsum, offs, cursor, N);
        fill_kernel<<<(E + 255) / 256, 256, 0, stream>>>(src, dst, cursor, colidx, E);
        agg_kernel<<<(N * 64 + 255) / 256, 256, 0, stream>>>(
            x, nullptr, dinv, offs, deg, colidx, src, dst, out, nullptr, N, E);
        int nTiles = (N + 15) / 16;
        gemm_kernel<<<(nTiles * 64 + 255) / 256, 256, 0, stream>>>(out, x, Wt, nullptr,
                                                                   scv, pov, nTiles);
    }
}